// Round 11
// baseline (2453.478 us; speedup 1.0000x reference)
//
#include <hip/hip_runtime.h>
#include <hip/hip_bf16.h>
#include <cmath>

#define NN 100000
#define EE 1250000
#define FIN 500
#define HH 64
#define CC 40
#define LL 16
#define ALPHA_C 0.1f
#define NPART 8
#define PSZ 12500            // NN / NPART
#define NN8 (NN * NPART)     // 800000
#define NB2 (NN8 / 256)      // 3125
#define LGRID 1792
#define NG 4                 // ceil(6250 / 1792)

typedef _Float16 f16x8 __attribute__((ext_vector_type(8)));
typedef _Float16 f16x4 __attribute__((ext_vector_type(4)));
typedef float f32x4 __attribute__((ext_vector_type(4)));

// ---------------- degree (for dinv) ----------------

__global__ void init_cnt_k(int* __restrict__ cnt) {
    int i = blockIdx.x * blockDim.x + threadIdx.x;
    if (i < NN) cnt[i] = 1;  // self-loop
}

__global__ void count_edges_k(const int* __restrict__ rows, int* __restrict__ cnt) {
    int e = blockIdx.x * blockDim.x + threadIdx.x;
    if (e < EE) atomicAdd(&cnt[rows[e]], 1);
}

__global__ void dinv_k(const int* __restrict__ cnt, float* __restrict__ dinv) {
    int i = blockIdx.x * blockDim.x + threadIdx.x;
    if (i < NN) dinv[i] = rsqrtf((float)cnt[i]);
}

// ---------------- phase-major CSR: bucket (p, n) = edges with dest n, source partition p ----------------

__global__ void init_cnt2_k(int* __restrict__ cnt2) {
    int i = blockIdx.x * blockDim.x + threadIdx.x;
    if (i < NN8) {
        int part = i / NN, n = i - part * NN;
        cnt2[i] = (n / PSZ == part) ? 1 : 0;  // self-loop in its own source partition
    }
}

__global__ void count2_k(const int* __restrict__ rows, const int* __restrict__ cols,
                         int* __restrict__ cnt2) {
    int e = blockIdx.x * blockDim.x + threadIdx.x;
    if (e < EE) {
        int r = rows[e], c = cols[e];
        atomicAdd(&cnt2[(c / PSZ) * NN + r], 1);
    }
}

__global__ __launch_bounds__(256) void blocksum2_k(const int* __restrict__ cnt2, int* __restrict__ bsum) {
    __shared__ int red[256];
    int tid = threadIdx.x;
    int i = blockIdx.x * 256 + tid;
    red[tid] = cnt2[i];  // NN8 is an exact multiple of 256*NB2
    __syncthreads();
    for (int ofs = 128; ofs > 0; ofs >>= 1) {
        if (tid < ofs) red[tid] += red[tid + ofs];
        __syncthreads();
    }
    if (tid == 0) bsum[blockIdx.x] = red[0];
}

__global__ __launch_bounds__(1024) void scanb2_k(int* __restrict__ bsum) {  // NB2 = 3125 elements
    __shared__ int part[1024];
    int tid = threadIdx.x;
    int base = tid * 4;
    int v0 = (base + 0 < NB2) ? bsum[base + 0] : 0;
    int v1 = (base + 1 < NB2) ? bsum[base + 1] : 0;
    int v2 = (base + 2 < NB2) ? bsum[base + 2] : 0;
    int v3 = (base + 3 < NB2) ? bsum[base + 3] : 0;
    part[tid] = v0 + v1 + v2 + v3;
    __syncthreads();
    for (int ofs = 1; ofs < 1024; ofs <<= 1) {
        int t = (tid >= ofs) ? part[tid - ofs] : 0;
        __syncthreads();
        part[tid] += t;
        __syncthreads();
    }
    int run = (tid > 0) ? part[tid - 1] : 0;
    if (base + 0 < NB2) { bsum[base + 0] = run; run += v0; }
    if (base + 1 < NB2) { bsum[base + 1] = run; run += v1; }
    if (base + 2 < NB2) { bsum[base + 2] = run; run += v2; }
    if (base + 3 < NB2) { bsum[base + 3] = run; run += v3; }
}

__global__ __launch_bounds__(256) void scatter2_k(const int* __restrict__ cnt2, const int* __restrict__ bsum,
                                                  int* __restrict__ rp2, int* __restrict__ cur2) {
    __shared__ int part[256];
    int tid = threadIdx.x;
    int i = blockIdx.x * 256 + tid;
    int v = cnt2[i];
    part[tid] = v;
    __syncthreads();
    for (int ofs = 1; ofs < 256; ofs <<= 1) {
        int t = (tid >= ofs) ? part[tid - ofs] : 0;
        __syncthreads();
        part[tid] += t;
        __syncthreads();
    }
    int incl = part[tid];
    int base = bsum[blockIdx.x];
    int excl = base + incl - v;
    rp2[i] = excl;
    cur2[i] = excl;
    if (i == NN8 - 1) rp2[NN8] = base + incl;
}

__global__ void fillself2_k(const float* __restrict__ dinv, int* __restrict__ cur2,
                            int2* __restrict__ edata2) {
    int n = blockIdx.x * blockDim.x + threadIdx.x;
    if (n < NN) {
        int p = atomicAdd(&cur2[(n / PSZ) * NN + n], 1);
        float d = dinv[n];
        edata2[p] = make_int2(n, __float_as_int(d * d));
    }
}

__global__ void filledges2_k(const int* __restrict__ rows, const int* __restrict__ cols,
                             const float* __restrict__ dinv, int* __restrict__ cur2,
                             int2* __restrict__ edata2) {
    int e = blockIdx.x * blockDim.x + threadIdx.x;
    if (e < EE) {
        int r = rows[e], c = cols[e];
        int p = atomicAdd(&cur2[(c / PSZ) * NN + r], 1);
        edata2[p] = make_int2(c, __float_as_int(dinv[r] * dinv[c]));
    }
}

// ---------------- input projection via MFMA: x0h = f16(relu(X @ W0 + b0)) ----------------

__global__ __launch_bounds__(256) void proj_k(const float* __restrict__ X, const float* __restrict__ W0,
                                              const float* __restrict__ b0,
                                              _Float16* __restrict__ x0h) {
    __shared__ _Float16 Asw[64 * 64];
    __shared__ _Float16 Bsw[64 * 64];
    char* AB = (char*)Asw;
    char* BB = (char*)Bsw;
    int tid = threadIdx.x;
    int lane = tid & 63, w = tid >> 6;
    int m0 = blockIdx.x * 64;
    f32x4 acc[4] = {};

    for (int k0 = 0; k0 < 512; k0 += 64) {
        for (int t = tid; t < 1024; t += 256) {
            int r = t >> 4, kq = t & 15;
            int k = k0 + kq * 4;
            int m = m0 + r;
            float4 v = make_float4(0.f, 0.f, 0.f, 0.f);
            if (m < NN && k < FIN) v = *(const float4*)(X + (size_t)m * FIN + k);
            f16x4 h;
            h[0] = (_Float16)v.x; h[1] = (_Float16)v.y;
            h[2] = (_Float16)v.z; h[3] = (_Float16)v.w;
            int b = (r * 128 + kq * 8) ^ ((r & 7) << 4);
            *(f16x4*)(AB + b) = h;
        }
        for (int t = tid; t < 1024; t += 256) {
            int kk = t >> 4, cq = t & 15;
            int k = k0 + kk;
            float4 v = make_float4(0.f, 0.f, 0.f, 0.f);
            if (k < FIN) v = *(const float4*)(W0 + (size_t)k * HH + cq * 4);
#pragma unroll
            for (int j = 0; j < 4; ++j) {
                int c = cq * 4 + j;
                int b = (c * 128 + kk * 2) ^ ((c & 7) << 4);
                *(_Float16*)(BB + b) = (_Float16)((&v.x)[j]);
            }
        }
        __syncthreads();
        int row = lane & 15;
        int ko = (lane >> 4) * 8;
        int ar = w * 16 + row;
#pragma unroll
        for (int st = 0; st < 2; ++st) {
            int k = ko + st * 32;
            f16x8 af = *(const f16x8*)(AB + ((ar * 128 + k * 2) ^ ((ar & 7) << 4)));
#pragma unroll
            for (int nt = 0; nt < 4; ++nt) {
                int c = nt * 16 + row;
                f16x8 bf = *(const f16x8*)(BB + ((c * 128 + k * 2) ^ ((c & 7) << 4)));
                acc[nt] = __builtin_amdgcn_mfma_f32_16x16x32_f16(af, bf, acc[nt], 0, 0, 0);
            }
        }
        __syncthreads();
    }
    int col0 = lane & 15;
    int rg = (lane >> 4) * 4;
#pragma unroll
    for (int nt = 0; nt < 4; ++nt) {
        int c = nt * 16 + col0;
        float bb = b0[c];
#pragma unroll
        for (int r = 0; r < 4; ++r) {
            int m = m0 + w * 16 + rg + r;
            if (m < NN) {
                float v = fmaxf(acc[nt][r] + bb, 0.f);
                x0h[(size_t)m * HH + c] = (_Float16)v;
            }
        }
    }
}

// ---------------- fused layer: phase-swept gather -> mix -> MFMA -> relu ----------------
// Source-partition phases keep a 1.6 MB slice of hin L2-resident on every XCD while
// all blocks gather from it. Register accumulators s[NG][4] persist across phases.

__global__ __launch_bounds__(256) void layer_k(const _Float16* __restrict__ hin,
                                               const _Float16* __restrict__ x0h,
                                               const int2* __restrict__ edata2,
                                               const int* __restrict__ rp2,
                                               const float* __restrict__ W, float beta,
                                               _Float16* __restrict__ hout) {
    __shared__ float Sb[16][68];
    __shared__ _Float16 Sh[16 * 64];
    __shared__ _Float16 Wt[64 * 64];
    char* ShB = (char*)Sh;
    char* WtB = (char*)Wt;
    int tid = threadIdx.x;

    for (int idx = tid; idx < HH * HH; idx += 256) {
        int k = idx >> 6, c = idx & 63;
        int b = (c * 128 + k * 2) ^ ((c & 7) << 4);
        *(_Float16*)(WtB + b) = (_Float16)W[idx];
    }

    int lane = tid & 63, w = tid >> 6;
    int bid = blockIdx.x;
    const float ob = 1.f - beta;

    float s[NG][4] = {};

    // phase-swept gather
    for (int p = 0; p < NPART; ++p) {
        const int pbase = p * NN;
#pragma unroll
        for (int gi = 0; gi < NG; ++gi) {
            int g = bid + gi * LGRID;
            if (g < NN / 16) {
                int nb = g * 16 + w * 4;
#pragma unroll
                for (int j = 0; j < 4; ++j) {
                    int n = nb + j;
                    int q  = __builtin_amdgcn_readfirstlane(rp2[pbase + n]);
                    int qe = __builtin_amdgcn_readfirstlane(rp2[pbase + n + 1]);
                    float a0 = 0.f, a1 = 0.f;
                    for (; q + 3 < qe; q += 4) {
                        int2 e0 = edata2[q], e1 = edata2[q + 1], e2 = edata2[q + 2], e3 = edata2[q + 3];
                        float v0 = (float)hin[(size_t)e0.x * HH + lane];
                        float v1 = (float)hin[(size_t)e1.x * HH + lane];
                        float v2 = (float)hin[(size_t)e2.x * HH + lane];
                        float v3 = (float)hin[(size_t)e3.x * HH + lane];
                        a0 += __int_as_float(e0.y) * v0;
                        a1 += __int_as_float(e1.y) * v1;
                        a0 += __int_as_float(e2.y) * v2;
                        a1 += __int_as_float(e3.y) * v3;
                    }
                    for (; q < qe; ++q) {
                        int2 e = edata2[q];
                        a0 += __int_as_float(e.y) * (float)hin[(size_t)e.x * HH + lane];
                    }
                    s[gi][j] += a0 + a1;
                }
            }
        }
    }

    // transform per group (all threads of a block share bid -> uniform control)
#pragma unroll 1
    for (int gi = 0; gi < NG; ++gi) {
        int g = bid + gi * LGRID;
        if (g >= NN / 16) break;
        int nbase = g * 16;
#pragma unroll
        for (int j = 0; j < 4; ++j) {
            int nl = w * 4 + j;
            int n = nbase + nl;
            float xv = (float)__builtin_nontemporal_load(&x0h[(size_t)n * HH + lane]);
            float sv = (1.f - ALPHA_C) * s[gi][j] + ALPHA_C * xv;
            Sb[nl][lane] = sv;
            int b = (nl * 128 + lane * 2) ^ ((nl & 7) << 4);
            *(_Float16*)(ShB + b) = (_Float16)sv;
        }
        __syncthreads();

        int col = w * 16 + (lane & 15);
        int row = lane & 15;
        int ko = (lane >> 4) * 8;
        f32x4 acc = {0.f, 0.f, 0.f, 0.f};
#pragma unroll
        for (int st = 0; st < 2; ++st) {
            int k0 = ko + st * 32;
            f16x8 af = *(const f16x8*)(ShB + ((row * 128 + k0 * 2) ^ ((row & 7) << 4)));
            f16x8 bf = *(const f16x8*)(WtB + ((col * 128 + k0 * 2) ^ ((col & 7) << 4)));
            acc = __builtin_amdgcn_mfma_f32_16x16x32_f16(af, bf, acc, 0, 0, 0);
        }
#pragma unroll
        for (int r = 0; r < 4; ++r) {
            int nl = (lane >> 4) * 4 + r;
            float sv = Sb[nl][col];
            float v = fmaxf(beta * acc[r] + ob * sv, 0.f);
            __builtin_nontemporal_store((_Float16)v, &hout[(size_t)(nbase + nl) * HH + col]);
        }
        __syncthreads();  // Sb/Sh reused by next gi
    }
}

// ---------------- output: out = h @ Wout + bout ----------------

__global__ __launch_bounds__(256) void out_k(const _Float16* __restrict__ h, const float* __restrict__ Wout,
                                             const float* __restrict__ bout, float* __restrict__ out) {
    __shared__ float Wl[64 * 40];
    __shared__ float bl[40];
    __shared__ float hrow[4][64];
    int tid = threadIdx.x;
    for (int idx = tid; idx < 64 * 40; idx += 256) Wl[idx] = Wout[idx];
    if (tid < 40) bl[tid] = bout[tid];
    __syncthreads();
    int lane = tid & 63, w = tid >> 6;
    int gw = blockIdx.x * 4 + w;
    int nw = gridDim.x * 4;
    for (int n = gw; n < NN; n += nw) {
        hrow[w][lane] = (float)h[(size_t)n * HH + lane];
        __builtin_amdgcn_s_waitcnt(0);  // lgkmcnt for same-wave LDS write->read
        if (lane < CC) {
            float acc = 0.f;
#pragma unroll
            for (int f = 0; f < 64; ++f) acc += hrow[w][f] * Wl[f * 40 + lane];
            out[(size_t)n * CC + lane] = acc + bl[lane];
        }
    }
}

// ---------------- launch ----------------

extern "C" void kernel_launch(void* const* d_in, const int* in_sizes, int n_in,
                              void* d_out, int out_size, void* d_ws, size_t ws_size,
                              hipStream_t stream) {
    const float* x    = (const float*)d_in[0];
    const int*   ei   = (const int*)d_in[1];
    const int*   rows = ei;
    const int*   cols = ei + EE;
    const float* W0   = (const float*)d_in[2];
    const float* b0   = (const float*)d_in[3];
    const float* Ws   = (const float*)d_in[4];
    const float* Wout = (const float*)d_in[5];
    const float* bout = (const float*)d_in[6];
    float* out = (float*)d_out;

    char* ws = (char*)d_ws;
    size_t o = 0;
    auto alloc = [&](size_t bytes) { void* p = ws + o; o += (bytes + 255) & ~(size_t)255; return p; };
    int*       cnt     = (int*)alloc((size_t)NN * 4);
    float*     dinv    = (float*)alloc((size_t)NN * 4);
    int*       cnt2    = (int*)alloc((size_t)NN8 * 4);
    int*       rp2     = (int*)alloc((size_t)(NN8 + 1) * 4);
    int*       cur2    = (int*)alloc((size_t)NN8 * 4);
    int*       bsum    = (int*)alloc((size_t)NB2 * 4);
    int2*      edata2  = (int2*)alloc((size_t)(EE + NN) * 8);
    _Float16*  x0h     = (_Float16*)alloc((size_t)NN * HH * 2);
    _Float16*  hA      = (_Float16*)alloc((size_t)NN * HH * 2);
    _Float16*  hB      = (_Float16*)alloc((size_t)NN * HH * 2);

    init_cnt_k<<<(NN + 255) / 256, 256, 0, stream>>>(cnt);
    count_edges_k<<<(EE + 255) / 256, 256, 0, stream>>>(rows, cnt);
    dinv_k<<<(NN + 255) / 256, 256, 0, stream>>>(cnt, dinv);

    init_cnt2_k<<<(NN8 + 255) / 256, 256, 0, stream>>>(cnt2);
    count2_k<<<(EE + 255) / 256, 256, 0, stream>>>(rows, cols, cnt2);
    blocksum2_k<<<NB2, 256, 0, stream>>>(cnt2, bsum);
    scanb2_k<<<1, 1024, 0, stream>>>(bsum);
    scatter2_k<<<NB2, 256, 0, stream>>>(cnt2, bsum, rp2, cur2);
    fillself2_k<<<(NN + 255) / 256, 256, 0, stream>>>(dinv, cur2, edata2);
    filledges2_k<<<(EE + 255) / 256, 256, 0, stream>>>(rows, cols, dinv, cur2, edata2);

    proj_k<<<(NN + 63) / 64, 256, 0, stream>>>(x, W0, b0, x0h);

    const _Float16* hin = x0h;
    _Float16* bufs[2] = {hA, hB};
    for (int l = 0; l < LL; ++l) {
        float beta = logf(0.5f / (float)(l + 1) + 1.0f);
        _Float16* hout = bufs[l & 1];
        layer_k<<<LGRID, 256, 0, stream>>>(hin, x0h, edata2, rp2,
                                           Ws + (size_t)l * HH * HH, beta, hout);
        hin = hout;
    }

    out_k<<<1024, 256, 0, stream>>>(hin, Wout, bout, out);
}